// Round 13
// baseline (141.974 us; speedup 1.0000x reference)
//
#include <hip/hip_runtime.h>
#include <hip/hip_bf16.h>
#include <stdint.h>

#define H 16
#define D 128
#define BM 128      // q rows per block (4 independent warps x 32)
#define BN 64       // kv rows per tile
#define NT 256

typedef __bf16 bf16_t;
typedef bf16_t bf16x8 __attribute__((ext_vector_type(8)));
typedef bf16_t bf16x2 __attribute__((ext_vector_type(2)));
typedef float f32x16 __attribute__((ext_vector_type(16)));

#define MFMA32(a, b, c) __builtin_amdgcn_mfma_f32_32x32x16_bf16(a, b, c, 0, 0, 0)

union FragU { uint32_t w[4]; bf16x8 v; };

static __device__ __forceinline__ uint32_t cvtpk_bf16(float lo, float hi) {
  uint32_t r;
  asm("v_cvt_pk_bf16_f32 %0, %1, %2" : "=v"(r) : "v"(lo), "v"(hi));
  return r;
}

// ---------------- convert kernels (one-time per launch) ----------------
// Both produce per-(seq,head,64-kv-tile) 16KB "fragment-block" images whose
// wave-level reads are contiguous 512B per half-wave (perfectly coalesced).

// K -> KC: per tile, 16 d-chunks (c2 = d/8) x 64 kv rows x 8 bf16.
// Frag (ct,ks) lane l reads slot ((ks*2 + l/32)*64 + ct*32 + (l&31)).
__global__ void conv_kc(const float* __restrict__ k, bf16_t* __restrict__ kc,
                        const int* __restrict__ cuk, int nseq) {
  int tile = blockIdx.x, h = blockIdx.y;
  int acc = 0, seq = -1, lt = 0, s0k = 0, Lk = 0, Lkp = 0;
  size_t vb = 0;
  for (int s = 0; s < nseq; ++s) {
    int Ls = cuk[s + 1] - cuk[s];
    int Lp = (Ls + 63) & ~63;
    int nt = Lp / 64;
    if (tile < acc + nt) { seq = s; lt = tile - acc; s0k = cuk[s]; Lk = Ls; Lkp = Lp; break; }
    acc += nt; vb += (size_t)H * D * Lp;
  }
  if (seq < 0) return;
  int r = threadIdx.x >> 2;          // kv row 0..63
  int quad = threadIdx.x & 3;        // d cols quad*32..+31
  int kv = lt * 64 + r; if (kv >= Lk) kv = Lk - 1;
  const float* p = k + ((size_t)(s0k + kv) * H + h) * D + quad * 32;
  bf16_t vals[32];
  #pragma unroll
  for (int i = 0; i < 8; ++i) {
    float4 f = *(const float4*)(p + i * 4);
    vals[i*4+0] = (bf16_t)f.x; vals[i*4+1] = (bf16_t)f.y;
    vals[i*4+2] = (bf16_t)f.z; vals[i*4+3] = (bf16_t)f.w;
  }
  bf16_t* dstT = kc + vb + (size_t)h * D * Lkp + (size_t)lt * 8192;
  #pragma unroll
  for (int i = 0; i < 4; ++i) {
    int c2 = quad * 4 + i;
    *(bf16x8*)(dstT + ((size_t)c2 * 64 + r) * 8) = *(bf16x8*)&vals[i * 8];
  }
}

// V -> VT: per tile, 8 kv-chunks (c = kv/8) x 128 d x 8 bf16 (as rounds 6-12).
__global__ void conv_vt(const float* __restrict__ v, bf16_t* __restrict__ vt,
                        const int* __restrict__ cuk, int nseq) {
  int tile = blockIdx.x, h = blockIdx.y;
  int acc = 0, seq = -1, lt = 0, s0k = 0, Lk = 0, Lkp = 0;
  size_t vb = 0;
  for (int s = 0; s < nseq; ++s) {
    int Ls = cuk[s + 1] - cuk[s];
    int Lp = (Ls + 63) & ~63;
    int nt = Lp / 64;
    if (tile < acc + nt) { seq = s; lt = tile - acc; s0k = cuk[s]; Lk = Ls; Lkp = Lp; break; }
    acc += nt; vb += (size_t)H * D * Lp;
  }
  if (seq < 0) return;
  int kv0 = lt * 64;
  int d = threadIdx.x;               // 0..127, coalesced reads
  bf16x8 w[8];
  #pragma unroll
  for (int j = 0; j < 64; ++j) {
    int kv = kv0 + j;
    int kvc = kv < Lk ? kv : Lk - 1;
    float val = v[((size_t)(s0k + kvc) * H + h) * D + d];
    w[j >> 3][j & 7] = (bf16_t)val;
  }
  bf16_t* dstT = vt + vb + (size_t)h * D * Lkp + (size_t)lt * 8192;
  #pragma unroll
  for (int c = 0; c < 8; ++c)
    *(bf16x8*)(dstT + ((size_t)c * 128 + d) * 8) = w[c];
}

// ---------------- main kernel: barrier-free, LDS-free ----------------

__global__ __launch_bounds__(NT, 3)
void fa_varlen13(const float* __restrict__ q,
                 const bf16_t* __restrict__ kc,
                 const bf16_t* __restrict__ vt,
                 const int* __restrict__ cuq,
                 const int* __restrict__ cuk,
                 float* __restrict__ out,
                 int nseq, int maxtiles)
{
  // ---- bijective XCD-chunked remap (m204), tile-fastest ----
  const int nwg = gridDim.x;
  const int orig = blockIdx.x;
  const int qq = nwg >> 3, rr = nwg & 7;
  const int xcd = orig & 7;
  const int wgid = (xcd < rr ? xcd * (qq + 1) : rr * (qq + 1) + (xcd - rr) * qq) + (orig >> 3);
  const int tile = wgid % maxtiles;
  const int h = wgid / maxtiles;

  int acc = 0, seq = -1, lt = 0, s0q = 0, s0k = 0, Lq = 0, Lk = 0, Lkp = 0;
  size_t vb = 0;
  for (int s = 0; s < nseq; ++s) {
    int a = cuq[s], b = cuq[s + 1];
    int Ls = b - a;
    int nt = (Ls + BM - 1) / BM;
    int Lks = cuk[s + 1] - cuk[s];
    int Lp = (Lks + 63) & ~63;
    if (tile < acc + nt) {
      seq = s; lt = tile - acc; s0q = a; Lq = Ls;
      s0k = cuk[s]; Lk = Lks; Lkp = Lp;
      break;
    }
    acc += nt; vb += (size_t)H * D * Lp;
  }
  if (seq < 0) return;

  const int q0 = lt * BM;
  const int tid = threadIdx.x;
  const int warp = tid >> 6;
  const int lane = tid & 63;
  const int lq = lane & 31;
  const int hi = lane >> 5;

  const float SC = 0.08838834764831845f * 1.44269504088896340f; // folded into Q

  // ---- Q fragments straight from global f32, pre-scaled by SC ----
  bf16x8 qf[8];
  {
    int qrow = q0 + warp * 32 + lq; if (qrow >= Lq) qrow = Lq - 1;
    const float* qp = q + ((size_t)(s0q + qrow) * H + h) * D;
    #pragma unroll
    for (int ks = 0; ks < 8; ++ks) {
      const float* p = qp + ks * 16 + hi * 8;
      float4 a = *(const float4*)p, b = *(const float4*)(p + 4);
      bf16x8 r;
      r[0] = (bf16_t)(a.x * SC); r[1] = (bf16_t)(a.y * SC);
      r[2] = (bf16_t)(a.z * SC); r[3] = (bf16_t)(a.w * SC);
      r[4] = (bf16_t)(b.x * SC); r[5] = (bf16_t)(b.y * SC);
      r[6] = (bf16_t)(b.z * SC); r[7] = (bf16_t)(b.w * SC);
      qf[ks] = r;
    }
  }

  const bf16_t* kcH = kc + vb + (size_t)h * D * Lkp;
  const bf16_t* vtH = vt + vb + (size_t)h * D * Lkp;

  f32x16 oacc[4];
  #pragma unroll
  for (int dt = 0; dt < 4; ++dt)
    #pragma unroll
    for (int r = 0; r < 16; ++r) oacc[dt][r] = 0.f;
  float m = -1e30f, l = 0.f;

  const int nkv = (Lk + BN - 1) / BN;

  for (int t = 0; t < nkv; ++t) {
    const int kvb = t * BN;
    const bf16_t* kcb = kcH + (size_t)t * 8192;
    const bf16_t* vtb = vtH + (size_t)t * 8192;
    const bool tail = (kvb + BN > Lk);

    #pragma unroll
    for (int ct = 0; ct < 2; ++ct) {
      // ---- QK^T swapped: operands loaded DIRECTLY from L2-resident frag
      //      blocks (contiguous 512B per half-wave). 2 independent chains. ----
      f32x16 sa, sb;
      #pragma unroll
      for (int r = 0; r < 16; ++r) { sa[r] = 0.f; sb[r] = 0.f; }
      __builtin_amdgcn_s_setprio(1);
      #pragma unroll
      for (int ks = 0; ks < 4; ++ks) {
        bf16x8 kfa = *(const bf16x8*)(kcb + ((((ks * 2 + hi) * 64) + ct * 32 + lq) << 3));
        sa = MFMA32(kfa, qf[ks], sa);
        bf16x8 kfb = *(const bf16x8*)(kcb + (((((ks + 4) * 2 + hi) * 64) + ct * 32 + lq) << 3));
        sb = MFMA32(kfb, qf[ks + 4], sb);
      }
      __builtin_amdgcn_s_setprio(0);

      // ---- online softmax, exp2 domain, defer-max THR=8 ----
      f32x16 st;
      #pragma unroll
      for (int r = 0; r < 16; ++r) {
        float x = sa[r] + sb[r];
        if (tail) {
          int kvi = kvb + ct * 32 + (r & 3) + 8 * (r >> 2) + 4 * hi;
          if (kvi >= Lk) x = -1e30f;
        }
        st[r] = x;
      }
      float m0;
      {
        float a0 = fmaxf(st[0], st[1]),  a1 = fmaxf(st[2], st[3]);
        float a2 = fmaxf(st[4], st[5]),  a3 = fmaxf(st[6], st[7]);
        float a4 = fmaxf(st[8], st[9]),  a5 = fmaxf(st[10], st[11]);
        float a6 = fmaxf(st[12], st[13]), a7 = fmaxf(st[14], st[15]);
        float b0 = fmaxf(a0, a1), b1 = fmaxf(a2, a3);
        float b2 = fmaxf(a4, a5), b3 = fmaxf(a6, a7);
        m0 = fmaxf(fmaxf(b0, b1), fmaxf(b2, b3));
      }
      float m1 = fmaxf(m0, __shfl_xor(m0, 32));
      bool trig = m1 > m + 8.0f;
      float mnew = trig ? m1 : m;
      float alpha = __builtin_amdgcn_exp2f(m - mnew);
      m = mnew;

      #pragma unroll
      for (int r = 0; r < 16; ++r)
        st[r] = __builtin_amdgcn_exp2f(st[r] - m);
      float psum;
      {
        float a0 = st[0] + st[1],  a1 = st[2] + st[3];
        float a2 = st[4] + st[5],  a3 = st[6] + st[7];
        float a4 = st[8] + st[9],  a5 = st[10] + st[11];
        float a6 = st[12] + st[13], a7 = st[14] + st[15];
        float b0 = a0 + a1, b1 = a2 + a3, b2 = a4 + a5, b3 = a6 + a7;
        psum = (b0 + b1) + (b2 + b3);
      }
      psum += __shfl_xor(psum, 32);
      l = l * alpha + psum;

      if (__any(alpha != 1.0f)) {
        #pragma unroll
        for (int r = 0; r < 16; ++r) {
          int cr = (r & 3) + 8 * (r >> 2) + 4 * hi;
          float a2 = __shfl(alpha, cr);
          #pragma unroll
          for (int dt = 0; dt < 4; ++dt) oacc[dt][r] *= a2;
        }
      }

      // ---- pack P -> bf16 A-frags (cvt_pk + permlane32_swap) ----
      uint32_t c0 = cvtpk_bf16(st[0],  st[1]),  c1 = cvtpk_bf16(st[2],  st[3]);
      uint32_t c2 = cvtpk_bf16(st[4],  st[5]),  c3 = cvtpk_bf16(st[6],  st[7]);
      uint32_t c4 = cvtpk_bf16(st[8],  st[9]),  c5 = cvtpk_bf16(st[10], st[11]);
      uint32_t c6 = cvtpk_bf16(st[12], st[13]), c7 = cvtpk_bf16(st[14], st[15]);
      { auto rr2 = __builtin_amdgcn_permlane32_swap(c0, c2, false, false); c0 = rr2[0]; c2 = rr2[1]; }
      { auto rr2 = __builtin_amdgcn_permlane32_swap(c1, c3, false, false); c1 = rr2[0]; c3 = rr2[1]; }
      { auto rr2 = __builtin_amdgcn_permlane32_swap(c4, c6, false, false); c4 = rr2[0]; c6 = rr2[1]; }
      { auto rr2 = __builtin_amdgcn_permlane32_swap(c5, c7, false, false); c5 = rr2[0]; c7 = rr2[1]; }
      FragU pa, pb;
      pa.w[0] = c0; pa.w[1] = c1; pa.w[2] = c2; pa.w[3] = c3;  // kv ct*32+0..15
      pb.w[0] = c4; pb.w[1] = c5; pb.w[2] = c6; pb.w[3] = c7;  // kv ct*32+16..31

      // ---- O += P V : V frags direct from global (contiguous) ----
      __builtin_amdgcn_s_setprio(1);
      #pragma unroll
      for (int dt = 0; dt < 4; ++dt) {
        bf16x8 vf0 = *(const bf16x8*)(vtb + ((((ct * 4 + hi) * 128) + dt * 32 + lq) << 3));
        oacc[dt] = MFMA32(pa.v, vf0, oacc[dt]);
        bf16x8 vf1 = *(const bf16x8*)(vtb + ((((ct * 4 + 2 + hi) * 128) + dt * 32 + lq) << 3));
        oacc[dt] = MFMA32(pb.v, vf1, oacc[dt]);
      }
      __builtin_amdgcn_s_setprio(0);
    }
  }

  // ---- epilogue: broadcast l via shfl, normalize, coalesced store ----
  #pragma unroll
  for (int r = 0; r < 16; ++r) {
    int cr = (r & 3) + 8 * (r >> 2) + 4 * hi;
    int qr = q0 + warp * 32 + cr;
    float lcr = __shfl(l, cr);
    if (qr < Lq) {
      float rn = 1.0f / lcr;
      float* op = out + ((size_t)(s0q + qr) * H + h) * D + lq;
      #pragma unroll
      for (int dt = 0; dt < 4; ++dt)
        op[dt * 32] = oacc[dt][r] * rn;
    }
  }
}

// ---------------- fallback (round-2 kernel, f32 direct, BM=128) ----------------

__global__ __launch_bounds__(256, 3)
void fa_varlen2(const float* __restrict__ q,
                const float* __restrict__ k,
                const float* __restrict__ v,
                const int* __restrict__ cuq,
                const int* __restrict__ cuk,
                float* __restrict__ out,
                int nseq)
{
  __shared__ alignas(16) bf16_t sBuf[128 * 128];
  __shared__ float sRed[4 * 32];
  bf16_t* sK  = sBuf;
  bf16_t* sVt = sBuf + 64 * 128;

  const int tile = blockIdx.x;
  const int h = blockIdx.y;

  int acc = 0, seq = -1, lt = 0, s0q = 0, s0k = 0, Lq = 0, Lk = 0;
  for (int s = 0; s < nseq; ++s) {
    int a = cuq[s], b = cuq[s + 1];
    int Ls = b - a;
    int nt = (Ls + 127) / 128;
    if (tile < acc + nt) {
      seq = s; lt = tile - acc; s0q = a; Lq = Ls;
      s0k = cuk[s]; Lk = cuk[s + 1] - s0k;
      break;
    }
    acc += nt;
  }
  if (seq < 0) return;

  const int q0 = lt * 128;
  const int tid = threadIdx.x;
  const int warp = tid >> 6;
  const int lane = tid & 63;
  const int lq = lane & 31;
  const int hi = lane >> 5;

  const float SC = 0.08838834764831845f * 1.44269504088896340f;

  #pragma unroll
  for (int ii = 0; ii < 8; ++ii) {
    int g = tid + ii * 256;
    int row = g >> 4, cc = g & 15;
    int gr = q0 + row; if (gr >= Lq) gr = Lq - 1;
    const float* p = q + ((size_t)(s0q + gr) * H + h) * D + cc * 8;
    float4 f0 = *(const float4*)p;
    float4 f1 = *(const float4*)(p + 4);
    bf16x8 w;
    w[0] = (bf16_t)f0.x; w[1] = (bf16_t)f0.y; w[2] = (bf16_t)f0.z; w[3] = (bf16_t)f0.w;
    w[4] = (bf16_t)f1.x; w[5] = (bf16_t)f1.y; w[6] = (bf16_t)f1.z; w[7] = (bf16_t)f1.w;
    *(bf16x8*)&sBuf[row * 128 + (((cc ^ (row & 7))) << 3)] = w;
  }
  __syncthreads();

  bf16x8 qf[8];
  {
    int row = warp * 32 + lq;
    #pragma unroll
    for (int ks = 0; ks < 8; ++ks) {
      int pos = (ks * 2 + hi) ^ (row & 7);
      qf[ks] = *(const bf16x8*)&sBuf[row * 128 + (pos << 3)];
    }
  }

  f32x16 oacc[4];
  #pragma unroll
  for (int dt = 0; dt < 4; ++dt)
    #pragma unroll
    for (int r = 0; r < 16; ++r) oacc[dt][r] = 0.f;
  float m = -1e30f, l = 0.f;

  const int nkv = (Lk + 63) / 64;
  for (int it = 0; it < nkv; ++it) {
    const int kv0 = it * 64;
    __syncthreads();

    #pragma unroll
    for (int ii = 0; ii < 4; ++ii) {
      int g = tid + ii * 256;
      int row = g >> 4, cc = g & 15;
      int gr = kv0 + row; if (gr >= Lk) gr = Lk - 1;
      const float* p = k + ((size_t)(s0k + gr) * H + h) * D + cc * 8;
      float4 f0 = *(const float4*)p;
      float4 f1 = *(const float4*)(p + 4);
      bf16x8 w;
      w[0] = (bf16_t)f0.x; w[1] = (bf16_t)f0.y; w[2] = (bf16_t)f0.z; w[3] = (bf16_t)f0.w;
      w[4] = (bf16_t)f1.x; w[5] = (bf16_t)f1.y; w[6] = (bf16_t)f1.z; w[7] = (bf16_t)f1.w;
      *(bf16x8*)&sK[row * 128 + (((cc ^ (row & 7))) << 3)] = w;
    }
    {
      int kp = tid & 31;
      int seg = tid >> 5;
      int r0 = kv0 + 2 * kp, r1 = r0 + 1;
      if (r0 >= Lk) r0 = Lk - 1;
      if (r1 >= Lk) r1 = Lk - 1;
      const float* p0 = v + ((size_t)(s0k + r0) * H + h) * D + seg * 16;
      const float* p1 = v + ((size_t)(s0k + r1) * H + h) * D + seg * 16;
      float va[16], vbf[16];
      *(float4*)&va[0]  = *(const float4*)p0;
      *(float4*)&va[4]  = *(const float4*)(p0 + 4);
      *(float4*)&va[8]  = *(const float4*)(p0 + 8);
      *(float4*)&va[12] = *(const float4*)(p0 + 12);
      *(float4*)&vbf[0]  = *(const float4*)p1;
      *(float4*)&vbf[4]  = *(const float4*)(p1 + 4);
      *(float4*)&vbf[8]  = *(const float4*)(p1 + 8);
      *(float4*)&vbf[12] = *(const float4*)(p1 + 12);
      int kvr = 2 * kp;
      #pragma unroll
      for (int i = 0; i < 16; ++i) {
        int d = seg * 16 + i;
        int pos = (kp >> 2) ^ (d & 7);
        bf16x2 w2; w2[0] = (bf16_t)va[i]; w2[1] = (bf16_t)vbf[i];
        *(bf16x2*)&sVt[d * 64 + (pos << 3) + (kvr & 7)] = w2;
      }
    }
    __syncthreads();

    const bool tail = (kv0 + 64 > Lk);

    #pragma unroll
    for (int ct = 0; ct < 2; ++ct) {
      f32x16 st;
      #pragma unroll
      for (int r = 0; r < 16; ++r) st[r] = 0.f;
      int krow = ct * 32 + lq;
      #pragma unroll
      for (int ks = 0; ks < 8; ++ks) {
        int pos = (ks * 2 + hi) ^ (krow & 7);
        bf16x8 kf = *(const bf16x8*)&sK[krow * 128 + (pos << 3)];
        st = MFMA32(kf, qf[ks], st);
      }

      float tmax = -1e30f;
      #pragma unroll
      for (int r = 0; r < 16; ++r) {
        float x = st[r] * SC;
        if (tail) {
          int kvi = kv0 + ct * 32 + (r & 3) + 8 * (r >> 2) + 4 * hi;
          if (kvi >= Lk) x = -1e30f;
        }
        st[r] = x;
        tmax = fmaxf(tmax, x);
      }
      tmax = fmaxf(tmax, __shfl_xor(tmax, 32));
      bool trig = tmax > m + 8.0f;
      float mnew = trig ? tmax : m;
      float alpha = exp2f(m - mnew);
      m = mnew;

      float psum = 0.f;
      #pragma unroll
      for (int r = 0; r < 16; ++r) {
        float e = exp2f(st[r] - m);
        st[r] = e;
        psum += e;
      }
      psum += __shfl_xor(psum, 32);
      l = l * alpha + psum;

      if (__any(alpha != 1.0f)) {
        if (hi == 0) sRed[warp * 32 + lq] = alpha;
        asm volatile("s_waitcnt lgkmcnt(0)" ::: "memory");
        #pragma unroll
        for (int r = 0; r < 16; ++r) {
          float a2 = sRed[warp * 32 + (r & 3) + 8 * (r >> 2) + 4 * hi];
          #pragma unroll
          for (int dt = 0; dt < 4; ++dt) oacc[dt][r] *= a2;
        }
      }

      uint32_t c0 = cvtpk_bf16(st[0],  st[1]),  c1 = cvtpk_bf16(st[2],  st[3]);
      uint32_t c2 = cvtpk_bf16(st[4],  st[5]),  c3 = cvtpk_bf16(st[6],  st[7]);
      uint32_t c4 = cvtpk_bf16(st[8],  st[9]),  c5 = cvtpk_bf16(st[10], st[11]);
      uint32_t c6 = cvtpk_bf16(st[12], st[13]), c7 = cvtpk_bf16(st[14], st[15]);
      { auto rr2 = __builtin_amdgcn_permlane32_swap(c0, c2, false, false); c0 = rr2[0]; c2 = rr2[1]; }
      { auto rr2 = __builtin_amdgcn_permlane32_swap(c1, c3, false, false); c1 = rr2[0]; c3 = rr2[1]; }
      { auto rr2 = __builtin_amdgcn_permlane32_swap(c4, c6, false, false); c4 = rr2[0]; c6 = rr2[1]; }
      { auto rr2 = __builtin_amdgcn_permlane32_swap(c5, c7, false, false); c5 = rr2[0]; c7 = rr2[1]; }
      FragU pa, pb;
      pa.w[0] = c0; pa.w[1] = c1; pa.w[2] = c2; pa.w[3] = c3;
      pb.w[0] = c4; pb.w[1] = c5; pb.w[2] = c6; pb.w[3] = c7;

      #pragma unroll
      for (int dt = 0; dt < 4; ++dt) {
        int drow = dt * 32 + lq;
        int pos0 = (ct * 4 + hi) ^ (drow & 7);
        bf16x8 vf0 = *(const bf16x8*)&sVt[drow * 64 + (pos0 << 3)];
        oacc[dt] = MFMA32(pa.v, vf0, oacc[dt]);
        int pos1 = (ct * 4 + 2 + hi) ^ (drow & 7);
        bf16x8 vf1 = *(const bf16x8*)&sVt[drow * 64 + (pos1 << 3)];
        oacc[dt] = MFMA32(pb.v, vf1, oacc[dt]);
      }
    }
  }

  if (hi == 0) sRed[warp * 32 + lq] = l;
  asm volatile("s_waitcnt lgkmcnt(0)" ::: "memory");
  #pragma unroll
  for (int r = 0; r < 16; ++r) {
    int cr = (r & 3) + 8 * (r >> 2) + 4 * hi;
    int qr = q0 + warp * 32 + cr;
    if (qr < Lq) {
      float rn = 1.0f / sRed[warp * 32 + cr];
      float* op = out + ((size_t)(s0q + qr) * H + h) * D + lq;
      #pragma unroll
      for (int dt = 0; dt < 4; ++dt)
        op[dt * 32] = oacc[dt][r] * rn;
    }
  }
}

extern "C" void kernel_launch(void* const* d_in, const int* in_sizes, int n_in,
                              void* d_out, int out_size, void* d_ws, size_t ws_size,
                              hipStream_t stream) {
  const float* q = (const float*)d_in[0];
  const float* k = (const float*)d_in[1];
  const float* v = (const float*)d_in[2];
  const int* cuq = (const int*)d_in[3];
  const int* cuk = (const int*)d_in[4];
  float* out = (float*)d_out;

  int total = in_sizes[0] / (H * D);
  int nseq = in_sizes[3] - 1;
  int maxtiles = (total + BM - 1) / BM + nseq;

  size_t pad = (size_t)nseq * 64 * H * D * 2 + 256;
  size_t needK = (size_t)in_sizes[1] * 2 + pad;
  size_t needV = (size_t)in_sizes[2] * 2 + pad;

  if (ws_size >= needK + needV) {
    bf16_t* kcb = (bf16_t*)d_ws;
    bf16_t* vtb = (bf16_t*)((char*)d_ws + needK);

    int maxvt = (total + 63) / 64 + nseq;
    dim3 gvt(maxvt, H);
    conv_kc<<<gvt, 256, 0, stream>>>(k, kcb, cuk, nseq);
    conv_vt<<<gvt, 128, 0, stream>>>(v, vtb, cuk, nseq);
    fa_varlen13<<<dim3(maxtiles * H), NT, 0, stream>>>(q, kcb, vtb, cuq, cuk, out, nseq, maxtiles);
  } else {
    dim3 grid(maxtiles, H);
    fa_varlen2<<<grid, 256, 0, stream>>>(q, k, v, cuq, cuk, out, nseq);
  }
}

// Round 15
// 122.417 us; speedup vs baseline: 1.1598x; 1.1598x over previous
//
#include <hip/hip_runtime.h>
#include <hip/hip_bf16.h>
#include <stdint.h>

#define H 16
#define D 128
#define BM 256      // q rows per block (8 warps x 32)
#define BN 64       // kv rows per tile
#define NW 8
#define NT 512

typedef __bf16 bf16_t;
typedef bf16_t bf16x8 __attribute__((ext_vector_type(8)));
typedef bf16_t bf16x2 __attribute__((ext_vector_type(2)));
typedef float f32x16 __attribute__((ext_vector_type(16)));

#define MFMA32(a, b, c) __builtin_amdgcn_mfma_f32_32x32x16_bf16(a, b, c, 0, 0, 0)

union FragU { uint32_t w[4]; bf16x8 v; };

static __device__ __forceinline__ uint32_t cvtpk_bf16(float lo, float hi) {
  uint32_t r;
  asm("v_cvt_pk_bf16_f32 %0, %1, %2" : "=v"(r) : "v"(lo), "v"(hi));
  return r;
}

static __device__ __forceinline__ void gld_lds16(const bf16_t* g, bf16_t* l) {
  __builtin_amdgcn_global_load_lds(
      (const __attribute__((address_space(1))) void*)g,
      (__attribute__((address_space(3))) void*)l, 16, 0, 0);
}

// cross-half exchange via permlane32_swap (VALU, vs ds_bpermute ~120cyc):
// lane i receives v[i^32].
// permlane32_swap(a,b): p[0] = {a.lo, b.lo}, p[1] = {a.hi, b.hi}.
// With a=b=v: lanes<32 need v.hi -> p[1]; lanes>=32 need v.lo -> p[0].
static __device__ __forceinline__ float xhalf(float v, int hi) {
  uint32_t b = __builtin_bit_cast(uint32_t, v);
  auto p = __builtin_amdgcn_permlane32_swap(b, b, false, false);
  uint32_t o = hi ? p[0] : p[1];
  return __builtin_bit_cast(float, o);
}

// ---------------- convert kernels (one-time per launch) ----------------

__global__ void conv_k(const float* __restrict__ kin, bf16_t* __restrict__ kb, int n8) {
  int i = blockIdx.x * blockDim.x + threadIdx.x;
  int stride = gridDim.x * blockDim.x;
  for (; i < n8; i += stride) {
    const float* p = kin + (size_t)i * 8;
    float4 a = *(const float4*)p, b = *(const float4*)(p + 4);
    bf16x8 w;
    w[0] = (bf16_t)a.x; w[1] = (bf16_t)a.y; w[2] = (bf16_t)a.z; w[3] = (bf16_t)a.w;
    w[4] = (bf16_t)b.x; w[5] = (bf16_t)b.y; w[6] = (bf16_t)b.z; w[7] = (bf16_t)b.w;
    *(bf16x8*)(kb + (size_t)i * 8) = w;
  }
}

// V[token][h][d] f32 -> per (seq,head): padded-64 kv tiles, each 64-kv tile is
// 1024 slots of 8 bf16: slot (c*128 + d) holds V[kv = tt*64 + c*8 .. +7][d].
__global__ void conv_vt(const float* __restrict__ v, bf16_t* __restrict__ vt,
                        const int* __restrict__ cuk, int nseq) {
  int tile = blockIdx.x, h = blockIdx.y;
  int acc = 0, seq = -1, lt = 0, s0k = 0, Lk = 0, Lkp = 0;
  size_t vb = 0;
  for (int s = 0; s < nseq; ++s) {
    int Ls = cuk[s + 1] - cuk[s];
    int Lp = (Ls + 63) & ~63;
    int nt = Lp / 64;
    if (tile < acc + nt) { seq = s; lt = tile - acc; s0k = cuk[s]; Lk = Ls; Lkp = Lp; break; }
    acc += nt; vb += (size_t)H * D * Lp;
  }
  if (seq < 0) return;
  int kv0 = lt * 64;
  int d = threadIdx.x;            // 0..127, coalesced reads
  bf16x8 w[8];
  #pragma unroll
  for (int j = 0; j < 64; ++j) {
    int kv = kv0 + j;
    int kvc = kv < Lk ? kv : Lk - 1;
    float val = v[((size_t)(s0k + kvc) * H + h) * D + d];
    w[j >> 3][j & 7] = (bf16_t)val;
  }
  bf16_t* dstT = vt + vb + (size_t)h * D * Lkp + (size_t)lt * 8192;
  #pragma unroll
  for (int c = 0; c < 8; ++c)
    *(bf16x8*)(dstT + ((size_t)c * 128 + d) * 8) = w[c];
}

// ---------------- main kernel: T15 pipeline + permlane reductions ----------------

__global__ __launch_bounds__(NT, 2)
void fa_varlen15(const float* __restrict__ q,
                 const bf16_t* __restrict__ kb,
                 const bf16_t* __restrict__ vt,
                 const int* __restrict__ cuq,
                 const int* __restrict__ cuk,
                 float* __restrict__ out,
                 int nseq, int maxtiles)
{
  __shared__ alignas(16) bf16_t sK[2][BN * D];        // 2 x 16KB, swizzled row-major
  __shared__ alignas(16) bf16_t sVt[3][8 * 128 * 8];  // 3 x 16KB, chunk-major [c][d][8]
  // total LDS = 80KB -> 2 blocks/CU

  // ---- bijective XCD-chunked remap (m204) ----
  const int nwg = gridDim.x;
  const int orig = blockIdx.x;
  const int qq = nwg >> 3, rr = nwg & 7;
  const int xcd = orig & 7;
  const int wgid = (xcd < rr ? xcd * (qq + 1) : rr * (qq + 1) + (xcd - rr) * qq) + (orig >> 3);
  const int tile = wgid % maxtiles;
  const int h = wgid / maxtiles;

  int acc = 0, seq = -1, lt = 0, s0q = 0, s0k = 0, Lq = 0, Lk = 0, Lkp = 0;
  size_t vb = 0;
  for (int s = 0; s < nseq; ++s) {
    int a = cuq[s], b = cuq[s + 1];
    int Ls = b - a;
    int nt = (Ls + BM - 1) / BM;
    int Lks = cuk[s + 1] - cuk[s];
    int Lp = (Lks + 63) & ~63;
    if (tile < acc + nt) {
      seq = s; lt = tile - acc; s0q = a; Lq = Ls;
      s0k = cuk[s]; Lk = Lks; Lkp = Lp;
      break;
    }
    acc += nt; vb += (size_t)H * D * Lp;
  }
  if (seq < 0) return;

  const int q0 = lt * BM;
  const int tid = threadIdx.x;
  const int lane = tid & 63;
  const int lq = lane & 31;
  const int hi = lane >> 5;

  const float SC = 0.08838834764831845f * 1.44269504088896340f; // folded into Q

  // ---- Q fragments straight from global f32, pre-scaled by SC ----
  bf16x8 qf[8];
  {
    int warp = tid >> 6;
    int qrow = q0 + warp * 32 + lq; if (qrow >= Lq) qrow = Lq - 1;
    const float* qp = q + ((size_t)(s0q + qrow) * H + h) * D;
    #pragma unroll
    for (int ks = 0; ks < 8; ++ks) {
      const float* p = qp + ks * 16 + hi * 8;
      float4 a = *(const float4*)p, b = *(const float4*)(p + 4);
      bf16x8 r;
      r[0] = (bf16_t)(a.x * SC); r[1] = (bf16_t)(a.y * SC);
      r[2] = (bf16_t)(a.z * SC); r[3] = (bf16_t)(a.w * SC);
      r[4] = (bf16_t)(b.x * SC); r[5] = (bf16_t)(b.y * SC);
      r[6] = (bf16_t)(b.z * SC); r[7] = (bf16_t)(b.w * SC);
      qf[ks] = r;
    }
  }

  const bf16_t* vsrcH = vt + vb + (size_t)h * D * Lkp;

  auto STAGE_K = [&](int tt, int buf) {
    const int kvb = tt * BN;
    #pragma unroll
    for (int i = 0; i < 2; ++i) {
      int g = tid + i * NT;                 // 0..1023
      int row = g >> 4, cc = g & 15;
      int kvr = kvb + row; if (kvr >= Lk) kvr = Lk - 1;
      const bf16_t* src = kb + ((size_t)(s0k + kvr) * H + h) * D + ((cc ^ (row & 7)) << 3);
      gld_lds16(src, &sK[buf][g * 8]);
    }
  };
  auto STAGE_V = [&](int tt, int buf) {
    const bf16_t* vsrc = vsrcH + (size_t)tt * 8192;
    #pragma unroll
    for (int i = 0; i < 2; ++i) {
      int g = tid + i * NT;
      gld_lds16(vsrc + (size_t)g * 8, &sVt[buf][g * 8]);
    }
  };

  f32x16 oacc[4];
  #pragma unroll
  for (int dt = 0; dt < 4; ++dt)
    #pragma unroll
    for (int r = 0; r < 16; ++r) oacc[dt][r] = 0.f;
  float m = -1e30f, l = 0.f;

  // pipeline state: P-frags / alpha / location of the PREVIOUS phase
  FragU paP, pbP;
  #pragma unroll
  for (int i = 0; i < 4; ++i) { paP.w[i] = 0u; pbP.w[i] = 0u; }
  float alphaP = 1.0f;
  int tP = 0, ctP = 0;

  const int nkv = (Lk + BN - 1) / BN;

  STAGE_K(0, 0);
  STAGE_V(0, 0);
  asm volatile("s_waitcnt vmcnt(0)" ::: "memory");
  __builtin_amdgcn_s_barrier();
  __builtin_amdgcn_sched_barrier(0);

  for (int t = 0; t < nkv; ++t) {
    const int kvb = t * BN;
    int tn = t + 1 < nkv ? t + 1 : nkv - 1;
    STAGE_K(tn, (t + 1) & 1);       // K first (drained by end-of-iter vmcnt(2))
    STAGE_V(tn, (t + 1) % 3);       // V second (may stay in flight 2 iters)

    const bf16_t* sKc = sK[t & 1];
    const bool tail = (kvb + BN > Lk);

    #pragma unroll
    for (int ct = 0; ct < 2; ++ct) {
      // ---- QK^T(p) swapped, 2 independent MFMA chains ----
      f32x16 sa, sb;
      #pragma unroll
      for (int r = 0; r < 16; ++r) { sa[r] = 0.f; sb[r] = 0.f; }
      int krow = ct * 32 + lq;
      __builtin_amdgcn_s_setprio(1);
      #pragma unroll
      for (int ks = 0; ks < 4; ++ks) {
        int posa = (ks * 2 + hi) ^ (krow & 7);
        bf16x8 kfa = *(const bf16x8*)&sKc[krow * 128 + (posa << 3)];
        sa = MFMA32(kfa, qf[ks], sa);
        int posb = ((ks + 4) * 2 + hi) ^ (krow & 7);
        bf16x8 kfb = *(const bf16x8*)&sKc[krow * 128 + (posb << 3)];
        sb = MFMA32(kfb, qf[ks + 4], sb);
      }
      __builtin_amdgcn_s_setprio(0);

      // ---- PV(p-1): rescale + 8 MFMAs; register-independent of softmax(p) ----
      if (__any(alphaP != 1.0f)) {
        #pragma unroll
        for (int r = 0; r < 16; ++r) {
          int cr = (r & 3) + 8 * (r >> 2) + 4 * hi;
          float a2 = __shfl(alphaP, cr);
          #pragma unroll
          for (int dt = 0; dt < 4; ++dt) oacc[dt][r] *= a2;
        }
      }
      {
        const bf16_t* sVp = sVt[tP % 3];
        #pragma unroll
        for (int dt = 0; dt < 4; ++dt) {
          int drow = dt * 32 + lq;
          bf16x8 vf0 = *(const bf16x8*)&sVp[((ctP * 4 + hi) * 128 + drow) << 3];
          oacc[dt] = MFMA32(paP.v, vf0, oacc[dt]);
          bf16x8 vf1 = *(const bf16x8*)&sVp[((ctP * 4 + 2 + hi) * 128 + drow) << 3];
          oacc[dt] = MFMA32(pbP.v, vf1, oacc[dt]);
        }
      }

      // ---- softmax(p), exp2 domain, defer-max THR=8, permlane reductions ----
      f32x16 st;
      #pragma unroll
      for (int r = 0; r < 16; ++r) {
        float x = sa[r] + sb[r];
        if (tail) {
          int kvi = kvb + ct * 32 + (r & 3) + 8 * (r >> 2) + 4 * hi;
          if (kvi >= Lk) x = -1e30f;
        }
        st[r] = x;
      }
      float m0;
      {
        float a0 = fmaxf(st[0], st[1]),  a1 = fmaxf(st[2], st[3]);
        float a2 = fmaxf(st[4], st[5]),  a3 = fmaxf(st[6], st[7]);
        float a4 = fmaxf(st[8], st[9]),  a5 = fmaxf(st[10], st[11]);
        float a6 = fmaxf(st[12], st[13]), a7 = fmaxf(st[14], st[15]);
        float b0 = fmaxf(a0, a1), b1 = fmaxf(a2, a3);
        float b2 = fmaxf(a4, a5), b3 = fmaxf(a6, a7);
        m0 = fmaxf(fmaxf(b0, b1), fmaxf(b2, b3));
      }
      float m1 = fmaxf(m0, xhalf(m0, hi));     // VALU cross-half, not ds_bpermute
      bool trig = m1 > m + 8.0f;
      float mnew = trig ? m1 : m;
      float alpha = __builtin_amdgcn_exp2f(m - mnew);
      m = mnew;

      #pragma unroll
      for (int r = 0; r < 16; ++r)
        st[r] = __builtin_amdgcn_exp2f(st[r] - m);
      float psum;
      {
        float a0 = st[0] + st[1],  a1 = st[2] + st[3];
        float a2 = st[4] + st[5],  a3 = st[6] + st[7];
        float a4 = st[8] + st[9],  a5 = st[10] + st[11];
        float a6 = st[12] + st[13], a7 = st[14] + st[15];
        float b0 = a0 + a1, b1 = a2 + a3, b2 = a4 + a5, b3 = a6 + a7;
        psum = (b0 + b1) + (b2 + b3);
      }
      psum += xhalf(psum, hi);                 // VALU cross-half
      l = l * alpha + psum;

      // ---- pack P(p) -> bf16 A-frags; becomes "previous" for next phase ----
      uint32_t c0 = cvtpk_bf16(st[0],  st[1]),  c1 = cvtpk_bf16(st[2],  st[3]);
      uint32_t c2 = cvtpk_bf16(st[4],  st[5]),  c3 = cvtpk_bf16(st[6],  st[7]);
      uint32_t c4 = cvtpk_bf16(st[8],  st[9]),  c5 = cvtpk_bf16(st[10], st[11]);
      uint32_t c6 = cvtpk_bf16(st[12], st[13]), c7 = cvtpk_bf16(st[14], st[15]);
      { auto rr2 = __builtin_amdgcn_permlane32_swap(c0, c2, false, false); c0 = rr2[0]; c2 = rr2[1]; }
      { auto rr2 = __builtin_amdgcn_permlane32_swap(c1, c3, false, false); c1 = rr2[0]; c3 = rr2[1]; }
      { auto rr2 = __builtin_amdgcn_permlane32_swap(c4, c6, false, false); c4 = rr2[0]; c6 = rr2[1]; }
      { auto rr2 = __builtin_amdgcn_permlane32_swap(c5, c7, false, false); c5 = rr2[0]; c7 = rr2[1]; }
      paP.w[0] = c0; paP.w[1] = c1; paP.w[2] = c2; paP.w[3] = c3;
      pbP.w[0] = c4; pbP.w[1] = c5; pbP.w[2] = c6; pbP.w[3] = c7;
      alphaP = alpha; tP = t; ctP = ct;
    }

    // K(t+1) landed (drain-all-but-2, V(t+1) stays flying); then barrier
    asm volatile("s_waitcnt vmcnt(2)" ::: "memory");
    __builtin_amdgcn_s_barrier();
    __builtin_amdgcn_sched_barrier(0);
  }

  // ---- final pipelined phase: PV(nkv-1, ct=1) ----
  if (__any(alphaP != 1.0f)) {
    #pragma unroll
    for (int r = 0; r < 16; ++r) {
      int cr = (r & 3) + 8 * (r >> 2) + 4 * hi;
      float a2 = __shfl(alphaP, cr);
      #pragma unroll
      for (int dt = 0; dt < 4; ++dt) oacc[dt][r] *= a2;
    }
  }
  {
    const bf16_t* sVp = sVt[tP % 3];
    #pragma unroll
    for (int dt = 0; dt < 4; ++dt) {
      int drow = dt * 32 + lq;
      bf16x8 vf0 = *(const bf16x8*)&sVp[((ctP * 4 + hi) * 128 + drow) << 3];
      oacc[dt] = MFMA32(paP.v, vf0, oacc[dt]);
      bf16x8 vf1 = *(const bf16x8*)&sVp[((ctP * 4 + 2 + hi) * 128 + drow) << 3];
      oacc[dt] = MFMA32(pbP.v, vf1, oacc[dt]);
    }
  }

  // ---- epilogue: broadcast l via shfl, normalize, coalesced store ----
  #pragma unroll
  for (int r = 0; r < 16; ++r) {
    int cr = (r & 3) + 8 * (r >> 2) + 4 * hi;
    int warp = tid >> 6;
    int qr = q0 + warp * 32 + cr;
    float lcr = __shfl(l, cr);
    if (qr < Lq) {
      float rn = 1.0f / lcr;
      float* op = out + ((size_t)(s0q + qr) * H + h) * D + lq;
      #pragma unroll
      for (int dt = 0; dt < 4; ++dt)
        op[dt * 32] = oacc[dt][r] * rn;
    }
  }
}

// ---------------- fallback (round-2 kernel, f32 direct, BM=128) ----------------

__global__ __launch_bounds__(256, 3)
void fa_varlen2(const float* __restrict__ q,
                const float* __restrict__ k,
                const float* __restrict__ v,
                const int* __restrict__ cuq,
                const int* __restrict__ cuk,
                float* __restrict__ out,
                int nseq)
{
  __shared__ alignas(16) bf16_t sBuf[128 * 128];
  __shared__ float sRed[4 * 32];
  bf16_t* sK  = sBuf;
  bf16_t* sVt = sBuf + 64 * 128;

  const int tile = blockIdx.x;
  const int h = blockIdx.y;

  int acc = 0, seq = -1, lt = 0, s0q = 0, s0k = 0, Lq = 0, Lk = 0;
  for (int s = 0; s < nseq; ++s) {
    int a = cuq[s], b = cuq[s + 1];
    int Ls = b - a;
    int nt = (Ls + 127) / 128;
    if (tile < acc + nt) {
      seq = s; lt = tile - acc; s0q = a; Lq = Ls;
      s0k = cuk[s]; Lk = cuk[s + 1] - s0k;
      break;
    }
    acc += nt;
  }
  if (seq < 0) return;

  const int q0 = lt * 128;
  const int tid = threadIdx.x;
  const int warp = tid >> 6;
  const int lane = tid & 63;
  const int lq = lane & 31;
  const int hi = lane >> 5;

  const float SC = 0.08838834764831845f * 1.44269504088896340f;

  #pragma unroll
  for (int ii = 0; ii < 8; ++ii) {
    int g = tid + ii * 256;
    int row = g >> 4, cc = g & 15;
    int gr = q0 + row; if (gr >= Lq) gr = Lq - 1;
    const float* p = q + ((size_t)(s0q + gr) * H + h) * D + cc * 8;
    float4 f0 = *(const float4*)p;
    float4 f1 = *(const float4*)(p + 4);
    bf16x8 w;
    w[0] = (bf16_t)f0.x; w[1] = (bf16_t)f0.y; w[2] = (bf16_t)f0.z; w[3] = (bf16_t)f0.w;
    w[4] = (bf16_t)f1.x; w[5] = (bf16_t)f1.y; w[6] = (bf16_t)f1.z; w[7] = (bf16_t)f1.w;
    *(bf16x8*)&sBuf[row * 128 + (((cc ^ (row & 7))) << 3)] = w;
  }
  __syncthreads();

  bf16x8 qf[8];
  {
    int row = warp * 32 + lq;
    #pragma unroll
    for (int ks = 0; ks < 8; ++ks) {
      int pos = (ks * 2 + hi) ^ (row & 7);
      qf[ks] = *(const bf16x8*)&sBuf[row * 128 + (pos << 3)];
    }
  }

  f32x16 oacc[4];
  #pragma unroll
  for (int dt = 0; dt < 4; ++dt)
    #pragma unroll
    for (int r = 0; r < 16; ++r) oacc[dt][r] = 0.f;
  float m = -1e30f, l = 0.f;

  const int nkv = (Lk + 63) / 64;
  for (int it = 0; it < nkv; ++it) {
    const int kv0 = it * 64;
    __syncthreads();

    #pragma unroll
    for (int ii = 0; ii < 4; ++ii) {
      int g = tid + ii * 256;
      int row = g >> 4, cc = g & 15;
      int gr = kv0 + row; if (gr >= Lk) gr = Lk - 1;
      const float* p = k + ((size_t)(s0k + gr) * H + h) * D + cc * 8;
      float4 f0 = *(const float4*)p;
      float4 f1 = *(const float4*)(p + 4);
      bf16x8 w;
      w[0] = (bf16_t)f0.x; w[1] = (bf16_t)f0.y; w[2] = (bf16_t)f0.z; w[3] = (bf16_t)f0.w;
      w[4] = (bf16_t)f1.x; w[5] = (bf16_t)f1.y; w[6] = (bf16_t)f1.z; w[7] = (bf16_t)f1.w;
      *(bf16x8*)&sK[row * 128 + (((cc ^ (row & 7))) << 3)] = w;
    }
    {
      int kp = tid & 31;
      int seg = tid >> 5;
      int r0 = kv0 + 2 * kp, r1 = r0 + 1;
      if (r0 >= Lk) r0 = Lk - 1;
      if (r1 >= Lk) r1 = Lk - 1;
      const float* p0 = v + ((size_t)(s0k + r0) * H + h) * D + seg * 16;
      const float* p1 = v + ((size_t)(s0k + r1) * H + h) * D + seg * 16;
      float va[16], vbf[16];
      *(float4*)&va[0]  = *(const float4*)p0;
      *(float4*)&va[4]  = *(const float4*)(p0 + 4);
      *(float4*)&va[8]  = *(const float4*)(p0 + 8);
      *(float4*)&va[12] = *(const float4*)(p0 + 12);
      *(float4*)&vbf[0]  = *(const float4*)p1;
      *(float4*)&vbf[4]  = *(const float4*)(p1 + 4);
      *(float4*)&vbf[8]  = *(const float4*)(p1 + 8);
      *(float4*)&vbf[12] = *(const float4*)(p1 + 12);
      int kvr = 2 * kp;
      #pragma unroll
      for (int i = 0; i < 16; ++i) {
        int d = seg * 16 + i;
        int pos = (kp >> 2) ^ (d & 7);
        bf16x2 w2; w2[0] = (bf16_t)va[i]; w2[1] = (bf16_t)vbf[i];
        *(bf16x2*)&sVt[d * 64 + (pos << 3) + (kvr & 7)] = w2;
      }
    }
    __syncthreads();

    const bool tail = (kv0 + 64 > Lk);

    #pragma unroll
    for (int ct = 0; ct < 2; ++ct) {
      f32x16 st;
      #pragma unroll
      for (int r = 0; r < 16; ++r) st[r] = 0.f;
      int krow = ct * 32 + lq;
      #pragma unroll
      for (int ks = 0; ks < 8; ++ks) {
        int pos = (ks * 2 + hi) ^ (krow & 7);
        bf16x8 kf = *(const bf16x8*)&sK[krow * 128 + (pos << 3)];
        st = MFMA32(kf, qf[ks], st);
      }

      float tmax = -1e30f;
      #pragma unroll
      for (int r = 0; r < 16; ++r) {
        float x = st[r] * SC;
        if (tail) {
          int kvi = kv0 + ct * 32 + (r & 3) + 8 * (r >> 2) + 4 * hi;
          if (kvi >= Lk) x = -1e30f;
        }
        st[r] = x;
        tmax = fmaxf(tmax, x);
      }
      tmax = fmaxf(tmax, __shfl_xor(tmax, 32));
      bool trig = tmax > m + 8.0f;
      float mnew = trig ? tmax : m;
      float alpha = exp2f(m - mnew);
      m = mnew;

      float psum = 0.f;
      #pragma unroll
      for (int r = 0; r < 16; ++r) {
        float e = exp2f(st[r] - m);
        st[r] = e;
        psum += e;
      }
      psum += __shfl_xor(psum, 32);
      l = l * alpha + psum;

      if (__any(alpha != 1.0f)) {
        if (hi == 0) sRed[warp * 32 + lq] = alpha;
        asm volatile("s_waitcnt lgkmcnt(0)" ::: "memory");
        #pragma unroll
        for (int r = 0; r < 16; ++r) {
          float a2 = sRed[warp * 32 + (r & 3) + 8 * (r >> 2) + 4 * hi];
          #pragma unroll
          for (int dt = 0; dt < 4; ++dt) oacc[dt][r] *= a2;
        }
      }

      uint32_t c0 = cvtpk_bf16(st[0],  st[1]),  c1 = cvtpk_bf16(st[2],  st[3]);
      uint32_t c2 = cvtpk_bf16(st[4],  st[5]),  c3 = cvtpk_bf16(st[6],  st[7]);
      uint32_t c4 = cvtpk_bf16(st[8],  st[9]),  c5 = cvtpk_bf16(st[10], st[11]);
      uint32_t c6 = cvtpk_bf16(st[12], st[13]), c7 = cvtpk_bf16(st[14], st[15]);
      { auto rr2 = __builtin_amdgcn_permlane32_swap(c0, c2, false, false); c0 = rr2[0]; c2 = rr2[1]; }
      { auto rr2 = __builtin_amdgcn_permlane32_swap(c1, c3, false, false); c1 = rr2[0]; c3 = rr2[1]; }
      { auto rr2 = __builtin_amdgcn_permlane32_swap(c4, c6, false, false); c4 = rr2[0]; c6 = rr2[1]; }
      { auto rr2 = __builtin_amdgcn_permlane32_swap(c5, c7, false, false); c5 = rr2[0]; c7 = rr2[1]; }
      FragU pa, pb;
      pa.w[0] = c0; pa.w[1] = c1; pa.w[2] = c2; pa.w[3] = c3;
      pb.w[0] = c4; pb.w[1] = c5; pb.w[2] = c6; pb.w[3] = c7;

      #pragma unroll
      for (int dt = 0; dt < 4; ++dt) {
        int drow = dt * 32 + lq;
        int pos0 = (ct * 4 + hi) ^ (drow & 7);
        bf16x8 vf0 = *(const bf16x8*)&sVt[drow * 64 + (pos0 << 3)];
        oacc[dt] = MFMA32(pa.v, vf0, oacc[dt]);
        int pos1 = (ct * 4 + 2 + hi) ^ (drow & 7);
        bf16x8 vf1 = *(const bf16x8*)&sVt[drow * 64 + (pos1 << 3)];
        oacc[dt] = MFMA32(pb.v, vf1, oacc[dt]);
      }
    }
  }

  if (hi == 0) sRed[warp * 32 + lq] = l;
  asm volatile("s_waitcnt lgkmcnt(0)" ::: "memory");
  #pragma unroll
  for (int r = 0; r < 16; ++r) {
    int cr = (r & 3) + 8 * (r >> 2) + 4 * hi;
    int qr = q0 + warp * 32 + cr;
    if (qr < Lq) {
      float rn = 1.0f / sRed[warp * 32 + cr];
      float* op = out + ((size_t)(s0q + qr) * H + h) * D + lq;
      #pragma unroll
      for (int dt = 0; dt < 4; ++dt)
        op[dt * 32] = oacc[dt][r] * rn;
    }
  }
}

extern "C" void kernel_launch(void* const* d_in, const int* in_sizes, int n_in,
                              void* d_out, int out_size, void* d_ws, size_t ws_size,
                              hipStream_t stream) {
  const float* q = (const float*)d_in[0];
  const float* k = (const float*)d_in[1];
  const float* v = (const float*)d_in[2];
  const int* cuq = (const int*)d_in[3];
  const int* cuk = (const int*)d_in[4];
  float* out = (float*)d_out;

  int total = in_sizes[0] / (H * D);
  int nseq = in_sizes[3] - 1;
  int maxtiles = (total + BM - 1) / BM + nseq;

  size_t needK = (size_t)in_sizes[1] * 2;
  size_t needV = (size_t)in_sizes[2] * 2 + (size_t)nseq * 64 * H * D * 2 + 256;

  if (ws_size >= needK + needV) {
    bf16_t* kb = (bf16_t*)d_ws;
    bf16_t* vtb = (bf16_t*)((char*)d_ws + needK);

    conv_k<<<1024, 256, 0, stream>>>(k, kb, in_sizes[1] / 8);
    int maxvt = (total + 63) / 64 + nseq;
    dim3 gvt(maxvt, H);
    conv_vt<<<gvt, 128, 0, stream>>>(v, vtb, cuk, nseq);
    fa_varlen15<<<dim3(maxtiles * H), NT, 0, stream>>>(q, kb, vtb, cuq, cuk, out, nseq, maxtiles);
  } else {
    int mt2 = (total + 127) / 128 + nseq;
    dim3 grid(mt2, H);
    fa_varlen2<<<grid, 256, 0, stream>>>(q, k, v, cuq, cuk, out, nseq);
  }
}